// Round 11
// baseline (3340.000 us; speedup 1.0000x reference)
//
#include <hip/hip_runtime.h>
#include <math.h>

#define B 64
#define H 512
#define MAXN 512
#define U 512
#define MM 32
#define IN_SZ 543      // H + M - 1
#define DEC_STRIDE 544

// ---- d_out layout (floats) ----
#define PTR_OFF 0
#define PTR_SZ (B*MAXN*MM)            // 1,048,576
#define CLOSS_OFF (PTR_OFF + PTR_SZ)  // 1,048,576
#define ENC_OFF (CLOSS_OFF + 1)       // 1,048,577  (NOT 16B aligned)
#define ENC_SZ (B*MAXN*H)             // 16,777,216
#define ADJ_OFF (ENC_OFF + ENC_SZ)    // 17,825,793

// ---- ws layout (floats) ----
#define EP_OFF 0
#define EP_SZ (B*MAXN*U)              // 16,777,216
#define GP_OFF (EP_OFF + EP_SZ)
#define GP_SZ (4*3*B*H)               // 393,216
#define HID0_OFF (GP_OFF + GP_SZ)
#define HID1_OFF (HID0_OFF + B*H)
#define W2H_OFF  (HID1_OFF + B*H)
#define COV_OFF  (W2H_OFF + B*H)
#define SC_OFF   (COV_OFF + B*MAXN)
#define DEC_OFF  (SC_OFF + B*MAXN)
#define TH_OFF   (DEC_OFF + B*DEC_STRIDE)   // B*32
#define CL_OFF   (TH_OFF + B*32)
#define OFFS_OFF (CL_OFF + 64)
#define W1H_OFF  (OFFS_OFF + 64)      // ushort[262144] (W1 hi bf16)
#define W1L_OFF  (W1H_OFF + 131072)   // ushort[262144] (W1 lo bf16)

typedef short bf16x8 __attribute__((ext_vector_type(8)));
typedef float f32x4  __attribute__((ext_vector_type(4)));

__device__ __forceinline__ float tanh_fast(float x){
    float e = __builtin_amdgcn_exp2f(x * 2.885390081777927f);
    return 1.0f - 2.0f * __builtin_amdgcn_rcpf(e + 1.0f);
}

__device__ __forceinline__ unsigned short f2bf(float x){
    unsigned int u = __float_as_uint(x);
    u = (u + 0x7fffu + ((u >> 16) & 1u)) >> 16;
    return (unsigned short)u;
}

// ---------------- init ----------------
__global__ void k_init(float* __restrict__ ws, float* __restrict__ out,
                       const float* __restrict__ hg, const int* __restrict__ lengths,
                       const float* __restrict__ W1){
    int gid = blockIdx.x*256 + threadIdx.x;
    int nth = gridDim.x*256;
    float* ptr = out + PTR_OFF;
    for (int i=gid;i<PTR_SZ;i+=nth) ptr[i]=0.f;
    float* cov = ws + COV_OFF;
    float* hid0 = ws + HID0_OFF;
    for (int i=gid;i<B*H;i+=nth){ cov[i]=0.f; hid0[i]=hg[i]; }
    unsigned short* w1h = (unsigned short*)(ws + W1H_OFF);
    unsigned short* w1l = (unsigned short*)(ws + W1L_OFF);
    for (int i=gid;i<512*512;i+=nth){
        float x = W1[i];
        unsigned short hb = f2bf(x);
        float hf = __uint_as_float(((unsigned int)hb)<<16);
        w1h[i] = hb;
        w1l[i] = f2bf(x - hf);
    }
    if (gid<64) (ws+CL_OFF)[gid]=0.f;
    if (gid==0){
        int* offs=(int*)(ws+OFFS_OFF); int acc=0;
        for(int b=0;b<B;b++){ offs[b]=acc; acc+=lengths[b]; }
    }
}

// ---------------- gather enc ----------------
__global__ __launch_bounds__(256) void k_gather(const float* __restrict__ h,
        const int* __restrict__ lengths, const float* __restrict__ offs_f,
        float* __restrict__ enc){
    const int* offs = (const int*)offs_f;
    int t = threadIdx.x;
    int row = blockIdx.x*2 + (t>>7);
    int c = (t&127)*4;
    int b = row >> 9, n = row & 511;
    int len = lengths[b];
    float4 v = make_float4(0.f,0.f,0.f,0.f);
    if (n < len){
        const float* p = h + (size_t)(offs[b]+n)*H + c;
        v = *(const float4*)p;
    }
    float* q = enc + (size_t)row*H + c;
    q[0]=v.x; q[1]=v.y; q[2]=v.z; q[3]=v.w;
}

// ---------------- ep = enc @ W1^T via split-bf16 MFMA (proven R9) ----------------
__global__ __launch_bounds__(256) void k_gemm_mfma(const float* __restrict__ enc,
        const unsigned short* __restrict__ w1h, const unsigned short* __restrict__ w1l,
        float* __restrict__ ep){
    __shared__ unsigned short sAH[128][40];
    __shared__ unsigned short sAL[128][40];
    __shared__ unsigned short sBH[128][40];
    __shared__ unsigned short sBL[128][40];
    int tid = threadIdx.x;
    int bm = blockIdx.x >> 2, bn = blockIdx.x & 3;
    int r0 = bm*128, u0 = bn*128;
    int wid = tid>>6, lane = tid&63;
    int wr = wid>>1, wc = wid&1;
    int lr = lane&15, lk = (lane>>4)*8;
    f32x4 acc[4][4];
#pragma unroll
    for (int i=0;i<4;i++)
#pragma unroll
        for (int j=0;j<4;j++) acc[i][j] = (f32x4){0.f,0.f,0.f,0.f};
    int rowA = tid>>2, seg = tid&3;
    for (int k0=0;k0<512;k0+=32){
#pragma unroll
        for (int half=0; half<2; ++half){
            int row = rowA + half*64;
            const float* asrc = &enc[(size_t)(r0+row)*512 + k0 + seg*8];
            bf16x8 vh, vl;
#pragma unroll
            for (int j=0;j<8;j++){
                float x = asrc[j];
                unsigned short hb = f2bf(x);
                float hf = __uint_as_float(((unsigned int)hb)<<16);
                vh[j] = (short)hb;
                vl[j] = (short)f2bf(x - hf);
            }
            *(bf16x8*)&sAH[row][seg*8] = vh;
            *(bf16x8*)&sAL[row][seg*8] = vl;
            size_t bidx = (size_t)(u0+row)*512 + k0 + seg*8;
            *(bf16x8*)&sBH[row][seg*8] = *(const bf16x8*)&w1h[bidx];
            *(bf16x8*)&sBL[row][seg*8] = *(const bf16x8*)&w1l[bidx];
        }
        __syncthreads();
        bf16x8 aH[4], aL[4], bH[4], bL[4];
#pragma unroll
        for (int f=0; f<4; f++){
            aH[f] = *(const bf16x8*)&sAH[wr*64+f*16+lr][lk];
            aL[f] = *(const bf16x8*)&sAL[wr*64+f*16+lr][lk];
            bH[f] = *(const bf16x8*)&sBH[wc*64+f*16+lr][lk];
            bL[f] = *(const bf16x8*)&sBL[wc*64+f*16+lr][lk];
        }
#pragma unroll
        for (int mf=0;mf<4;mf++){
#pragma unroll
            for (int nf=0;nf<4;nf++){
                acc[mf][nf] = __builtin_amdgcn_mfma_f32_16x16x32_bf16(aH[mf], bH[nf], acc[mf][nf], 0,0,0);
                acc[mf][nf] = __builtin_amdgcn_mfma_f32_16x16x32_bf16(aH[mf], bL[nf], acc[mf][nf], 0,0,0);
                acc[mf][nf] = __builtin_amdgcn_mfma_f32_16x16x32_bf16(aL[mf], bH[nf], acc[mf][nf], 0,0,0);
            }
        }
        __syncthreads();
    }
#pragma unroll
    for (int mf=0;mf<4;mf++){
#pragma unroll
        for (int nf=0;nf<4;nf++){
#pragma unroll
            for (int r=0;r<4;r++){
                int row = r0 + wr*64 + mf*16 + (lane>>4)*4 + r;
                int col = u0 + wc*64 + nf*16 + lr;
                ep[(size_t)row*512 + col] = acc[mf][nf][r];
            }
        }
    }
}

// ---------------- gruPS: [soft(i-1) prologue on ih-blocks] + GRU partial dots ----------------
// 512 blocks: s=blk>>7 (0,1: ih slices; 2,3: hh slices), hc=blk&127 (4 h per block).
// s<2 blocks recompute softmax/argmax of step-1 (bit-identical across blocks);
// designated blocks (s==0, hc<64) do cov/closs/pointer side effects for b=hc.
__global__ __launch_bounds__(256) void k_gruPS(
        const float* __restrict__ hid_in,
        const float* __restrict__ w_ih, const float* __restrict__ w_hh,
        const float* __restrict__ sc, const float* __restrict__ gum,
        const int* __restrict__ lengths, const float* __restrict__ enc,
        const float* __restrict__ th, float* __restrict__ cov,
        float* __restrict__ clb, float* __restrict__ pointer,
        float* __restrict__ gp, int step){
    __shared__ float As[64][36];
    __shared__ float Ws[12][36];
    __shared__ float red[256];
    __shared__ int   sNs[64];
    __shared__ float sZ[64];
    int tid=threadIdx.x, b=tid&63, q=tid>>6;
    int s = blockIdx.x >> 7;
    int hc = blockIdx.x & 127;
    int h0 = hc * 4;

    // ---- prologue: recompute softmax/argmax of step-1 (ih blocks only) ----
    if (s < 2 && step > 0){
        int wv = tid>>6, lane = tid&63;
        for (int bb=wv; bb<64; bb+=4){
            int len = lengths[bb];
            const float* scb = &sc[bb*512];
            const float* gb  = &gum[((size_t)(step-1)*64+bb)*512];
            float e[8]; float zs=0.f;
#pragma unroll
            for (int c=0;c<8;c++){
                int n = c*64 + lane;
                float ev = (n<len)? expf(scb[n]) : 0.f;
                e[c]=ev; zs += ev;
            }
#pragma unroll
            for (int m=1;m<64;m<<=1) zs += __shfl_xor(zs, m, 64);
            float best=-1e38f; int bi=0;
#pragma unroll
            for (int c=0;c<8;c++){
                int n = c*64 + lane;
                float lg = logf(e[c]/zs + 1e-12f) + gb[n];
                if (lg > best){ best=lg; bi=n; }
            }
#pragma unroll
            for (int m=1;m<64;m<<=1){
                float ob = __shfl_xor(best, m, 64);
                int   oi = __shfl_xor(bi, m, 64);
                if (ob > best || (ob==best && oi<bi)){ best=ob; bi=oi; }
            }
            if (lane==0){ sNs[bb]=bi; sZ[bb]=zs; }
        }
        __syncthreads();
        // designated side effects for b = hc (once per b per step)
        if (s==0 && hc < 64){
            int bb = hc;
            int len = lengths[bb];
            float Z = sZ[bb];
            int n0=tid, n1=tid+256;
            float e0=(n0<len)? expf(sc[bb*512+n0]) : 0.f;
            float e1=(n1<len)? expf(sc[bb*512+n1]) : 0.f;
            float a0=e0/Z, a1=e1/Z;
            float c0=cov[bb*512+n0], c1=cov[bb*512+n1];
            red[tid]=fminf(a0,c0)+fminf(a1,c1); __syncthreads();
            for(int o=128;o>=1;o>>=1){ if(tid<o) red[tid]+=red[tid+o]; __syncthreads(); }
            if(tid==0){
                clb[bb] += red[0];
                pointer[bb*16384 + sNs[bb]*32 + (step-1)] = 1.f;
            }
            cov[bb*512+n0]=c0+a0;
            cov[bb*512+n1]=c1+a1;
            __syncthreads();
        }
    }

    // ---- matmul partials (R5-identical core; As source per s) ----
    int kbeg, kend; const float* W; int wstride;
    if (s==0){ kbeg=0;   kend=288;   W=w_ih; wstride=IN_SZ; }
    else if(s==1){ kbeg=288; kend=IN_SZ; W=w_ih; wstride=IN_SZ; }
    else if(s==2){ kbeg=0;   kend=256; W=w_hh; wstride=512; }
    else         { kbeg=256; kend=512; W=w_hh; wstride=512; }
    float a0=0.f,a1=0.f,a2=0.f;
    for (int k0=kbeg; k0<kend; k0+=32){
        if (s < 2){
            // dec-side: rows from enc[ns[b]] (k<512) / th (512<=k<543), zeros at step 0
            for (int it=0;it<2;it++){
                int idx=tid+it*256; int row=idx>>3, c=idx&7; int k=k0+c*4;
                float vx0=0.f, vx1=0.f, vx2=0.f, vx3=0.f;
                if (step > 0){
                    int nsr = sNs[row];
                    const float* er = &enc[((size_t)(row*512 + nsr))*512];
                    const float* tr = &th[row*32];
#pragma unroll
                    for (int j=0;j<4;j++){
                        int kk = k + j;
                        float val;
                        if (kk < 512) val = er[kk];
                        else if (kk < IN_SZ) val = tr[kk-512];
                        else val = 0.f;
                        if (j==0) vx0=val; else if(j==1) vx1=val;
                        else if (j==2) vx2=val; else vx3=val;
                    }
                }
                *(float4*)&As[row][c*4]=make_float4(vx0,vx1,vx2,vx3);
            }
        } else {
            for (int it=0;it<2;it++){
                int idx=tid+it*256; int row=idx>>3,c=idx&7; int k=k0+c*4;
                *(float4*)&As[row][c*4] = *(const float4*)&hid_in[row*512+k];
            }
        }
        if (tid<96){
            int rr=tid>>3, c=tid&7; int g=rr>>2, qq=rr&3;
            int j=g*512 + h0+qq; int k=k0+c*4;
            float4 v=make_float4(0.f,0.f,0.f,0.f);
            const float* p=&W[(size_t)j*wstride+k];
            if (wstride==512){
                v=*(const float4*)p;
            } else {
                if(k<kend)v.x=p[0]; if(k+1<kend)v.y=p[1];
                if(k+2<kend)v.z=p[2]; if(k+3<kend)v.w=p[3];
            }
            *(float4*)&Ws[rr][c*4]=v;
        }
        __syncthreads();
#pragma unroll
        for (int kk=0;kk<32;kk+=4){
            float4 a=*(const float4*)&As[b][kk];
            float4 w0=*(const float4*)&Ws[q][kk];
            float4 w1=*(const float4*)&Ws[4+q][kk];
            float4 w2=*(const float4*)&Ws[8+q][kk];
            a0 += a.x*w0.x + a.y*w0.y + a.z*w0.z + a.w*w0.w;
            a1 += a.x*w1.x + a.y*w1.y + a.z*w1.z + a.w*w1.w;
            a2 += a.x*w2.x + a.y*w2.y + a.z*w2.z + a.w*w2.w;
        }
        __syncthreads();
    }
    int h = h0 + q;
    gp[((s*3+0)*64+b)*512 + h] = a0;
    gp[((s*3+1)*64+b)*512 + h] = a1;
    gp[((s*3+2)*64+b)*512 + h] = a2;
}

// ---------------- mid: GRU epilogue + w2h + theta (R5, theta -> th buffer) ----------------
__global__ __launch_bounds__(512) void k_mid(const float* __restrict__ gp,
        const float* __restrict__ hid_in, float* __restrict__ hid_out,
        const float* __restrict__ b_ih, const float* __restrict__ b_hh,
        const float* __restrict__ W2, const float* __restrict__ Wf,
        const float* __restrict__ bf,
        float* __restrict__ w2h, float* __restrict__ th,
        float* __restrict__ adj, int step){
    __shared__ float sH[512];
    int b = blockIdx.x >> 2, uc = blockIdx.x & 3;
    int tid = threadIdx.x;
    {
        int h = tid;
        float gI0 = gp[((0*3+0)*64+b)*512+h] + gp[((1*3+0)*64+b)*512+h];
        float gI1 = gp[((0*3+1)*64+b)*512+h] + gp[((1*3+1)*64+b)*512+h];
        float gI2 = gp[((0*3+2)*64+b)*512+h] + gp[((1*3+2)*64+b)*512+h];
        float gH0 = gp[((2*3+0)*64+b)*512+h] + gp[((3*3+0)*64+b)*512+h];
        float gH1 = gp[((2*3+1)*64+b)*512+h] + gp[((3*3+1)*64+b)*512+h];
        float gH2 = gp[((2*3+2)*64+b)*512+h] + gp[((3*3+2)*64+b)*512+h];
        float gi0=gI0+b_ih[h],     gh0=gH0+b_hh[h];
        float gi1=gI1+b_ih[512+h], gh1=gH1+b_hh[512+h];
        float gi2=gI2+b_ih[1024+h],gh2=gH2+b_hh[1024+h];
        float r=1.f/(1.f+expf(-(gi0+gh0)));
        float z=1.f/(1.f+expf(-(gi1+gh1)));
        float nn=tanhf(gi2 + r*gh2);
        float hv=(1.f-z)*nn + z*hid_in[b*512+h];
        sH[h]=hv;
        if (uc==0) hid_out[b*512+h]=hv;
    }
    __syncthreads();
    int wv=tid>>6, lane=tid&63;
    for (int ul=wv; ul<128; ul+=8){
        int u = uc*128 + ul;
        const float* wr = &W2[(size_t)u*512];
        float acc=0.f;
#pragma unroll
        for (int t=0;t<8;t++){ int k=t*64+lane; acc += wr[k]*sH[k]; }
#pragma unroll
        for (int m=1;m<64;m<<=1) acc += __shfl_xor(acc, m, 64);
        if (lane==0) w2h[b*512+u]=acc;
    }
    if (uc==0){
        for (int ul=wv; ul<31; ul+=8){
            const float* wr = &Wf[(size_t)ul*512];
            float acc=0.f;
#pragma unroll
            for (int t=0;t<8;t++){ int k=t*64+lane; acc += wr[k]*sH[k]; }
#pragma unroll
            for (int m=1;m<64;m<<=1) acc += __shfl_xor(acc, m, 64);
            if (lane==0){
                float thv = 1.f/(1.f+expf(-(acc + bf[ul])));
                thv = (ul < step) ? thv : 0.f;
                th[b*32 + ul] = thv;
                adj[b*992 + ul*32 + step] = thv;
            }
        }
    }
}

// ---------------- scores: 1024 blocks = (b, nc of 16), 256 threads (proven R5) ----------------
__global__ __launch_bounds__(256) void k_scores(const float* __restrict__ ep,
        const float* __restrict__ w2h, const float* __restrict__ cov,
        const float* __restrict__ wc, const float* __restrict__ v,
        const int* __restrict__ lengths, float* __restrict__ sc){
    __shared__ float sW[512], sV[512], sC[512];
    int b = blockIdx.x >> 4, nc = blockIdx.x & 15;
    int len = lengths[b];
    if (nc*32 >= len) return;
    int tid=threadIdx.x;
    for (int idx=tid; idx<384; idx+=256){
        int which = idx>>7, c = (idx&127)*4;
        float4 val;
        if (which==0) val=*(const float4*)&w2h[b*512+c];
        else if (which==1) val=*(const float4*)&v[c];
        else val=*(const float4*)&wc[c];
        float* dst = (which==0)?sW:((which==1)?sV:sC);
        *(float4*)&dst[c]=val;
    }
    __syncthreads();
    int wv=tid>>6, lane=tid&63;
    float4 vv0=*(const float4*)&sV[lane*8], vv1=*(const float4*)&sV[lane*8+4];
    float4 cc0=*(const float4*)&sC[lane*8], cc1=*(const float4*)&sC[lane*8+4];
    float4 ww0=*(const float4*)&sW[lane*8], ww1=*(const float4*)&sW[lane*8+4];
#pragma unroll
    for (int r=0;r<8;r++){
        int n = nc*32 + wv*8 + r;
        float cb = cov[b*512+n];
        const float4* rr = (const float4*)&ep[((size_t)b*512+n)*512 + lane*8];
        float4 e0=rr[0], e1=rr[1];
        float acc;
        acc  = tanh_fast(e0.x + ww0.x + cb*cc0.x)*vv0.x;
        acc += tanh_fast(e0.y + ww0.y + cb*cc0.y)*vv0.y;
        acc += tanh_fast(e0.z + ww0.z + cb*cc0.z)*vv0.z;
        acc += tanh_fast(e0.w + ww0.w + cb*cc0.w)*vv0.w;
        acc += tanh_fast(e1.x + ww1.x + cb*cc1.x)*vv1.x;
        acc += tanh_fast(e1.y + ww1.y + cb*cc1.y)*vv1.y;
        acc += tanh_fast(e1.z + ww1.z + cb*cc1.z)*vv1.z;
        acc += tanh_fast(e1.w + ww1.w + cb*cc1.w)*vv1.w;
#pragma unroll
        for (int m=1;m<64;m<<=1) acc += __shfl_xor(acc, m, 64);
        if (lane==0) sc[b*512+n]=acc;
    }
}

// ---------------- soft (used once, for step 31): proven R9 body ----------------
__global__ __launch_bounds__(512) void k_soft(const float* __restrict__ sc,
        const float* __restrict__ gum, const int* __restrict__ lengths,
        const float* __restrict__ enc, float* __restrict__ cov,
        float* __restrict__ dec_in, float* __restrict__ closs_b,
        float* __restrict__ pointer, int step){
    __shared__ float red[512];
    __shared__ int  redi[512];
    int b=blockIdx.x, n=threadIdx.x;
    int len=lengths[b];
    float e = (n<len)? expf(sc[b*512+n]) : 0.f;
    red[n]=e; __syncthreads();
    for(int o=256;o>=1;o>>=1){ if(n<o) red[n]+=red[n+o]; __syncthreads(); }
    float Z=red[0]; __syncthreads();
    float att=e/Z;
    float c=cov[b*512+n];
    red[n]=fminf(att,c); __syncthreads();
    for(int o=256;o>=1;o>>=1){ if(n<o) red[n]+=red[n+o]; __syncthreads(); }
    if(n==0) closs_b[b]+=red[0];
    __syncthreads();
    cov[b*512+n]=c+att;
    float lg=logf(att+1e-12f)+gum[((size_t)step*64+b)*512+n];
    red[n]=lg; redi[n]=n; __syncthreads();
    for(int o=256;o>=1;o>>=1){
        if(n<o && red[n+o]>red[n]){ red[n]=red[n+o]; redi[n]=redi[n+o]; }
        __syncthreads();
    }
    int ns=redi[0];
    if(n==0) pointer[b*16384 + ns*32 + step]=1.f;
    dec_in[b*DEC_STRIDE+n]=enc[((size_t)b*512+ns)*512+n];
}

__global__ void k_final(const float* __restrict__ closs_b, float* __restrict__ out){
    if (threadIdx.x==0 && blockIdx.x==0){
        float s=0.f;
        for(int b=0;b<B;b++) s+=closs_b[b];
        out[CLOSS_OFF]=s/64.f;
    }
}

extern "C" void kernel_launch(void* const* d_in, const int* in_sizes, int n_in,
                              void* d_out, int out_size, void* d_ws, size_t ws_size,
                              hipStream_t stream){
    const float* h      = (const float*)d_in[0];
    const float* hg     = (const float*)d_in[1];
    const int*   lengths= (const int*)  d_in[2];
    const float* gumbel = (const float*)d_in[3];
    const float* W1     = (const float*)d_in[4];
    const float* W2     = (const float*)d_in[5];
    const float* wc     = (const float*)d_in[6];
    const float* v      = (const float*)d_in[7];
    const float* w_ih   = (const float*)d_in[8];
    const float* w_hh   = (const float*)d_in[9];
    const float* b_ih   = (const float*)d_in[10];
    const float* b_hh   = (const float*)d_in[11];
    const float* Wf     = (const float*)d_in[12];
    const float* bf     = (const float*)d_in[13];
    float* out = (float*)d_out;
    float* ws  = (float*)d_ws;
    float* enc = out + ENC_OFF;
    float* adj = out + ADJ_OFF;
    float* pointer = out + PTR_OFF;
    float* ep   = ws + EP_OFF;
    float* gp   = ws + GP_OFF;
    float* hidA = ws + HID0_OFF;
    float* hidB = ws + HID1_OFF;
    float* w2h  = ws + W2H_OFF;
    float* cov  = ws + COV_OFF;
    float* sc   = ws + SC_OFF;
    float* dec  = ws + DEC_OFF;
    float* th   = ws + TH_OFF;
    float* clb  = ws + CL_OFF;
    const unsigned short* w1h = (const unsigned short*)(ws + W1H_OFF);
    const unsigned short* w1l = (const unsigned short*)(ws + W1L_OFF);

    hipLaunchKernelGGL(k_init,     dim3(512),  dim3(256), 0, stream, ws, out, hg, lengths, W1);
    hipLaunchKernelGGL(k_gather,   dim3(16384),dim3(256), 0, stream, h, lengths, ws+OFFS_OFF, enc);
    hipLaunchKernelGGL(k_gemm_mfma,dim3(1024), dim3(256), 0, stream, enc, w1h, w1l, ep);

    for (int i=0;i<MM;i++){
        const float* hin = (i&1)? hidB : hidA;
        float*       hout= (i&1)? hidA : hidB;
        hipLaunchKernelGGL(k_gruPS,  dim3(512),  dim3(256), 0, stream,
                           hin, w_ih, w_hh, sc, gumbel, lengths, enc, th,
                           cov, clb, pointer, gp, i);
        hipLaunchKernelGGL(k_mid,    dim3(256),  dim3(512), 0, stream,
                           gp, hin, hout, b_ih, b_hh, W2, Wf, bf, w2h, th, adj, i);
        hipLaunchKernelGGL(k_scores, dim3(1024), dim3(256), 0, stream,
                           ep, w2h, cov, wc, v, lengths, sc);
    }
    hipLaunchKernelGGL(k_soft,  dim3(64), dim3(512), 0, stream,
                       sc, gumbel, lengths, enc, cov, dec, clb, pointer, MM-1);
    hipLaunchKernelGGL(k_final, dim3(1),  dim3(64),  0, stream, clb, out);
}

// Round 12
// 2091.948 us; speedup vs baseline: 1.5966x; 1.5966x over previous
//
#include <hip/hip_runtime.h>
#include <math.h>

#define B 64
#define H 512
#define MAXN 512
#define U 512
#define MM 32
#define IN_SZ 543      // H + M - 1
#define DEC_STRIDE 544

// ---- d_out layout (floats) ----
#define PTR_OFF 0
#define PTR_SZ (B*MAXN*MM)            // 1,048,576
#define CLOSS_OFF (PTR_OFF + PTR_SZ)  // 1,048,576
#define ENC_OFF (CLOSS_OFF + 1)       // 1,048,577  (NOT 16B aligned)
#define ENC_SZ (B*MAXN*H)             // 16,777,216
#define ADJ_OFF (ENC_OFF + ENC_SZ)    // 17,825,793

// ---- ws layout (floats) ----
#define EP_OFF 0
#define EP_SZ (B*MAXN*U)              // 16,777,216
#define GP_OFF (EP_OFF + EP_SZ)
#define GP_SZ (4*3*B*H)               // 393,216
#define HID0_OFF (GP_OFF + GP_SZ)
#define HID1_OFF (HID0_OFF + B*H)
#define W2H_OFF  (HID1_OFF + B*H)
#define COV_OFF  (W2H_OFF + B*H)
#define DEC_OFF  (COV_OFF + B*MAXN)
#define CL_OFF   (DEC_OFF + B*DEC_STRIDE)
#define OFFS_OFF (CL_OFF + 64)
#define W1H_OFF  (OFFS_OFF + 64)      // ushort[262144] (W1 hi bf16)
#define W1L_OFF  (W1H_OFF + 131072)   // ushort[262144] (W1 lo bf16)

typedef short bf16x8 __attribute__((ext_vector_type(8)));
typedef float f32x4  __attribute__((ext_vector_type(4)));

__device__ __forceinline__ float tanh_fast(float x){
    float e = __builtin_amdgcn_exp2f(x * 2.885390081777927f);
    return 1.0f - 2.0f * __builtin_amdgcn_rcpf(e + 1.0f);
}

__device__ __forceinline__ unsigned short f2bf(float x){
    unsigned int u = __float_as_uint(x);
    u = (u + 0x7fffu + ((u >> 16) & 1u)) >> 16;
    return (unsigned short)u;
}

// ---------------- init ----------------
__global__ void k_init(float* __restrict__ ws, float* __restrict__ out,
                       const float* __restrict__ hg, const int* __restrict__ lengths,
                       const float* __restrict__ W1){
    int gid = blockIdx.x*256 + threadIdx.x;
    int nth = gridDim.x*256;
    float* ptr = out + PTR_OFF;
    for (int i=gid;i<PTR_SZ;i+=nth) ptr[i]=0.f;
    float* dec = ws + DEC_OFF;
    for (int i=gid;i<B*DEC_STRIDE;i+=nth) dec[i]=0.f;
    float* cov = ws + COV_OFF;
    float* hid0 = ws + HID0_OFF;
    for (int i=gid;i<B*H;i+=nth){ cov[i]=0.f; hid0[i]=hg[i]; }
    unsigned short* w1h = (unsigned short*)(ws + W1H_OFF);
    unsigned short* w1l = (unsigned short*)(ws + W1L_OFF);
    for (int i=gid;i<512*512;i+=nth){
        float x = W1[i];
        unsigned short hb = f2bf(x);
        float hf = __uint_as_float(((unsigned int)hb)<<16);
        w1h[i] = hb;
        w1l[i] = f2bf(x - hf);
    }
    if (gid<64) (ws+CL_OFF)[gid]=0.f;
    if (gid==0){
        int* offs=(int*)(ws+OFFS_OFF); int acc=0;
        for(int b=0;b<B;b++){ offs[b]=acc; acc+=lengths[b]; }
    }
}

// ---------------- gather enc ----------------
__global__ __launch_bounds__(256) void k_gather(const float* __restrict__ h,
        const int* __restrict__ lengths, const float* __restrict__ offs_f,
        float* __restrict__ enc){
    const int* offs = (const int*)offs_f;
    int t = threadIdx.x;
    int row = blockIdx.x*2 + (t>>7);
    int c = (t&127)*4;
    int b = row >> 9, n = row & 511;
    int len = lengths[b];
    float4 v = make_float4(0.f,0.f,0.f,0.f);
    if (n < len){
        const float* p = h + (size_t)(offs[b]+n)*H + c;
        v = *(const float4*)p;
    }
    float* q = enc + (size_t)row*H + c;
    q[0]=v.x; q[1]=v.y; q[2]=v.z; q[3]=v.w;
}

// ---------------- ep = enc @ W1^T via split-bf16 MFMA (proven R9) ----------------
__global__ __launch_bounds__(256) void k_gemm_mfma(const float* __restrict__ enc,
        const unsigned short* __restrict__ w1h, const unsigned short* __restrict__ w1l,
        float* __restrict__ ep){
    __shared__ unsigned short sAH[128][40];
    __shared__ unsigned short sAL[128][40];
    __shared__ unsigned short sBH[128][40];
    __shared__ unsigned short sBL[128][40];
    int tid = threadIdx.x;
    int bm = blockIdx.x >> 2, bn = blockIdx.x & 3;
    int r0 = bm*128, u0 = bn*128;
    int wid = tid>>6, lane = tid&63;
    int wr = wid>>1, wc = wid&1;
    int lr = lane&15, lk = (lane>>4)*8;
    f32x4 acc[4][4];
#pragma unroll
    for (int i=0;i<4;i++)
#pragma unroll
        for (int j=0;j<4;j++) acc[i][j] = (f32x4){0.f,0.f,0.f,0.f};
    int rowA = tid>>2, seg = tid&3;
    for (int k0=0;k0<512;k0+=32){
#pragma unroll
        for (int half=0; half<2; ++half){
            int row = rowA + half*64;
            const float* asrc = &enc[(size_t)(r0+row)*512 + k0 + seg*8];
            bf16x8 vh, vl;
#pragma unroll
            for (int j=0;j<8;j++){
                float x = asrc[j];
                unsigned short hb = f2bf(x);
                float hf = __uint_as_float(((unsigned int)hb)<<16);
                vh[j] = (short)hb;
                vl[j] = (short)f2bf(x - hf);
            }
            *(bf16x8*)&sAH[row][seg*8] = vh;
            *(bf16x8*)&sAL[row][seg*8] = vl;
            size_t bidx = (size_t)(u0+row)*512 + k0 + seg*8;
            *(bf16x8*)&sBH[row][seg*8] = *(const bf16x8*)&w1h[bidx];
            *(bf16x8*)&sBL[row][seg*8] = *(const bf16x8*)&w1l[bidx];
        }
        __syncthreads();
        bf16x8 aH[4], aL[4], bH[4], bL[4];
#pragma unroll
        for (int f=0; f<4; f++){
            aH[f] = *(const bf16x8*)&sAH[wr*64+f*16+lr][lk];
            aL[f] = *(const bf16x8*)&sAL[wr*64+f*16+lr][lk];
            bH[f] = *(const bf16x8*)&sBH[wc*64+f*16+lr][lk];
            bL[f] = *(const bf16x8*)&sBL[wc*64+f*16+lr][lk];
        }
#pragma unroll
        for (int mf=0;mf<4;mf++){
#pragma unroll
            for (int nf=0;nf<4;nf++){
                acc[mf][nf] = __builtin_amdgcn_mfma_f32_16x16x32_bf16(aH[mf], bH[nf], acc[mf][nf], 0,0,0);
                acc[mf][nf] = __builtin_amdgcn_mfma_f32_16x16x32_bf16(aH[mf], bL[nf], acc[mf][nf], 0,0,0);
                acc[mf][nf] = __builtin_amdgcn_mfma_f32_16x16x32_bf16(aL[mf], bH[nf], acc[mf][nf], 0,0,0);
            }
        }
        __syncthreads();
    }
#pragma unroll
    for (int mf=0;mf<4;mf++){
#pragma unroll
        for (int nf=0;nf<4;nf++){
#pragma unroll
            for (int r=0;r<4;r++){
                int row = r0 + wr*64 + mf*16 + (lane>>4)*4 + r;
                int col = u0 + wc*64 + nf*16 + lr;
                ep[(size_t)row*512 + col] = acc[mf][nf][r];
            }
        }
    }
}

// ---------------- GRU partial dots (proven R5) ----------------
__global__ __launch_bounds__(256) void k_gruP(const float* __restrict__ dec_in,
        const float* __restrict__ hid_in,
        const float* __restrict__ w_ih, const float* __restrict__ w_hh,
        float* __restrict__ gp){
    __shared__ float As[64][36];
    __shared__ float Ws[12][36];
    int tid=threadIdx.x, b=tid&63, q=tid>>6;
    int s = blockIdx.x >> 7;
    int h0 = (int)(blockIdx.x & 127) * 4;
    const float* xs; int xstride, kbeg, kend; const float* W; int wstride;
    if (s==0){ xs=dec_in; xstride=DEC_STRIDE; kbeg=0;   kend=288;   W=w_ih; wstride=IN_SZ; }
    else if(s==1){ xs=dec_in; xstride=DEC_STRIDE; kbeg=288; kend=IN_SZ; W=w_ih; wstride=IN_SZ; }
    else if(s==2){ xs=hid_in; xstride=512; kbeg=0;   kend=256; W=w_hh; wstride=512; }
    else         { xs=hid_in; xstride=512; kbeg=256; kend=512; W=w_hh; wstride=512; }
    float a0=0.f,a1=0.f,a2=0.f;
    for (int k0=kbeg; k0<kend; k0+=32){
        for (int it=0;it<2;it++){
            int idx=tid+it*256; int row=idx>>3, c=idx&7; int k=k0+c*4;
            float4 v=make_float4(0.f,0.f,0.f,0.f);
            const float* p=&xs[row*xstride+k];
            if (k+3 < kend) v=*(const float4*)p;
            else { if(k<kend)v.x=p[0]; if(k+1<kend)v.y=p[1]; if(k+2<kend)v.z=p[2]; }
            *(float4*)&As[row][c*4]=v;
        }
        if (tid<96){
            int rr=tid>>3, c=tid&7; int g=rr>>2, qq=rr&3;
            int j=g*512 + h0+qq; int k=k0+c*4;
            float4 v=make_float4(0.f,0.f,0.f,0.f);
            const float* p=&W[(size_t)j*wstride+k];
            if (wstride==512){
                v=*(const float4*)p;
            } else {
                if(k<kend)v.x=p[0]; if(k+1<kend)v.y=p[1];
                if(k+2<kend)v.z=p[2]; if(k+3<kend)v.w=p[3];
            }
            *(float4*)&Ws[rr][c*4]=v;
        }
        __syncthreads();
#pragma unroll
        for (int kk=0;kk<32;kk+=4){
            float4 a=*(const float4*)&As[b][kk];
            float4 w0=*(const float4*)&Ws[q][kk];
            float4 w1=*(const float4*)&Ws[4+q][kk];
            float4 w2=*(const float4*)&Ws[8+q][kk];
            a0 += a.x*w0.x + a.y*w0.y + a.z*w0.z + a.w*w0.w;
            a1 += a.x*w1.x + a.y*w1.y + a.z*w1.z + a.w*w1.w;
            a2 += a.x*w2.x + a.y*w2.y + a.z*w2.z + a.w*w2.w;
        }
        __syncthreads();
    }
    int h = h0 + q;
    gp[((s*3+0)*64+b)*512 + h] = a0;
    gp[((s*3+1)*64+b)*512 + h] = a1;
    gp[((s*3+2)*64+b)*512 + h] = a2;
}

// ---------------- mid: GRU epilogue + w2h + theta (proven R5) ----------------
__global__ __launch_bounds__(512) void k_mid(const float* __restrict__ gp,
        const float* __restrict__ hid_in, float* __restrict__ hid_out,
        const float* __restrict__ b_ih, const float* __restrict__ b_hh,
        const float* __restrict__ W2, const float* __restrict__ Wf,
        const float* __restrict__ bf,
        float* __restrict__ w2h, float* __restrict__ dec_in,
        float* __restrict__ adj, int step){
    __shared__ float sH[512];
    int b = blockIdx.x >> 2, uc = blockIdx.x & 3;
    int tid = threadIdx.x;
    {
        int h = tid;
        float gI0 = gp[((0*3+0)*64+b)*512+h] + gp[((1*3+0)*64+b)*512+h];
        float gI1 = gp[((0*3+1)*64+b)*512+h] + gp[((1*3+1)*64+b)*512+h];
        float gI2 = gp[((0*3+2)*64+b)*512+h] + gp[((1*3+2)*64+b)*512+h];
        float gH0 = gp[((2*3+0)*64+b)*512+h] + gp[((3*3+0)*64+b)*512+h];
        float gH1 = gp[((2*3+1)*64+b)*512+h] + gp[((3*3+1)*64+b)*512+h];
        float gH2 = gp[((2*3+2)*64+b)*512+h] + gp[((3*3+2)*64+b)*512+h];
        float gi0=gI0+b_ih[h],     gh0=gH0+b_hh[h];
        float gi1=gI1+b_ih[512+h], gh1=gH1+b_hh[512+h];
        float gi2=gI2+b_ih[1024+h],gh2=gH2+b_hh[1024+h];
        float r=1.f/(1.f+expf(-(gi0+gh0)));
        float z=1.f/(1.f+expf(-(gi1+gh1)));
        float nn=tanhf(gi2 + r*gh2);
        float hv=(1.f-z)*nn + z*hid_in[b*512+h];
        sH[h]=hv;
        if (uc==0) hid_out[b*512+h]=hv;
    }
    __syncthreads();
    int wv=tid>>6, lane=tid&63;
    for (int ul=wv; ul<128; ul+=8){
        int u = uc*128 + ul;
        const float* wr = &W2[(size_t)u*512];
        float acc=0.f;
#pragma unroll
        for (int t=0;t<8;t++){ int k=t*64+lane; acc += wr[k]*sH[k]; }
#pragma unroll
        for (int m=1;m<64;m<<=1) acc += __shfl_xor(acc, m, 64);
        if (lane==0) w2h[b*512+u]=acc;
    }
    if (uc==0){
        for (int ul=wv; ul<31; ul+=8){
            const float* wr = &Wf[(size_t)ul*512];
            float acc=0.f;
#pragma unroll
            for (int t=0;t<8;t++){ int k=t*64+lane; acc += wr[k]*sH[k]; }
#pragma unroll
            for (int m=1;m<64;m<<=1) acc += __shfl_xor(acc, m, 64);
            if (lane==0){
                float th = 1.f/(1.f+expf(-(acc + bf[ul])));
                th = (ul < step) ? th : 0.f;
                dec_in[b*DEC_STRIDE + 512 + ul] = th;
                adj[b*992 + ul*32 + step] = th;
            }
        }
    }
}

// ---------------- fused scores+soft: 64 blocks (one per b) x 1024 threads ----------------
// scores: 16 waves, n strided by 16, unroll-4 for 4 outstanding ep row loads;
// soft tail: R4/R9-validated body on threads 0..511.
__global__ __launch_bounds__(1024) void k_scsoft(
        const float* __restrict__ ep, const float* __restrict__ w2h,
        const float* __restrict__ wc, const float* __restrict__ v,
        const int* __restrict__ lengths, const float* __restrict__ gum,
        const float* __restrict__ enc,
        float* __restrict__ cov, float* __restrict__ dec_in,
        float* __restrict__ closs_b, float* __restrict__ pointer, int step){
    __shared__ float sW[512], sV[512], sC[512], sCov[512];
    __shared__ float sSc[512];
    __shared__ float red[512];
    __shared__ int  redi[512];
    const int b = blockIdx.x, tid = threadIdx.x;
    const int wv = tid>>6, lane = tid&63;
    const int len = lengths[b];

    {   // stage w2h, v, wc, cov (4 arrays x 512 floats, 128 float4s each)
        int seg = tid >> 7, off = (tid & 127) * 4;
        if (seg==0)      *(float4*)&sW[off]   = *(const float4*)&w2h[b*512+off];
        else if (seg==1) *(float4*)&sV[off]   = *(const float4*)&v[off];
        else if (seg==2) *(float4*)&sC[off]   = *(const float4*)&wc[off];
        else if (seg==3) *(float4*)&sCov[off] = *(const float4*)&cov[b*512+off];
        else if (seg==4) { if ((tid&127)<128) *(float4*)&sSc[off] = make_float4(0.f,0.f,0.f,0.f); }
    }
    __syncthreads();

    // ---- scores ----
    {
        float4 vv0=*(const float4*)&sV[lane*8], vv1=*(const float4*)&sV[lane*8+4];
        float4 cc0=*(const float4*)&sC[lane*8], cc1=*(const float4*)&sC[lane*8+4];
        float4 ww0=*(const float4*)&sW[lane*8], ww1=*(const float4*)&sW[lane*8+4];
        // len is 256 or 512 -> rows per wave = len/16 (16 or 32), unroll by 4
        int rows = len >> 4;
#pragma unroll 4
        for (int r=0; r<rows; ++r){
            int n = r*16 + wv;
            float cb = sCov[n];
            const float4* rr = (const float4*)&ep[((size_t)b*512+n)*512 + lane*8];
            float4 e0=rr[0], e1=rr[1];
            float acc;
            acc  = tanh_fast(e0.x + ww0.x + cb*cc0.x)*vv0.x;
            acc += tanh_fast(e0.y + ww0.y + cb*cc0.y)*vv0.y;
            acc += tanh_fast(e0.z + ww0.z + cb*cc0.z)*vv0.z;
            acc += tanh_fast(e0.w + ww0.w + cb*cc0.w)*vv0.w;
            acc += tanh_fast(e1.x + ww1.x + cb*cc1.x)*vv1.x;
            acc += tanh_fast(e1.y + ww1.y + cb*cc1.y)*vv1.y;
            acc += tanh_fast(e1.z + ww1.z + cb*cc1.z)*vv1.z;
            acc += tanh_fast(e1.w + ww1.w + cb*cc1.w)*vv1.w;
#pragma unroll
            for (int m=1;m<64;m<<=1) acc += __shfl_xor(acc, m, 64);
            if (lane==0) sSc[n]=acc;
        }
    }
    __syncthreads();

    // ---- soft tail (threads 0..511 active per-element; all sync) ----
    int n = tid;
    float e = 0.f;
    if (n < 512){ e = (n < len) ? expf(sSc[n]) : 0.f; red[n] = e; }
    __syncthreads();
    for (int o=256;o>=1;o>>=1){ if (n<o) red[n]+=red[n+o]; __syncthreads(); }
    float Z = red[0];
    __syncthreads();
    float att = 0.f, cvo = 0.f;
    if (n < 512){
        att = e / Z;
        cvo = sCov[n];
        red[n] = fminf(att, cvo);
    }
    __syncthreads();
    for (int o=256;o>=1;o>>=1){ if (n<o) red[n]+=red[n+o]; __syncthreads(); }
    if (tid==0) closs_b[b] += red[0];
    __syncthreads();
    if (n < 512){
        cov[b*512+n] = cvo + att;
        float lg = logf(att + 1e-12f) + gum[((size_t)step*64+b)*512 + n];
        red[n] = lg; redi[n] = n;
    }
    __syncthreads();
    for (int o=256;o>=1;o>>=1){
        if (n<o && red[n+o]>red[n]){ red[n]=red[n+o]; redi[n]=redi[n+o]; }
        __syncthreads();
    }
    int ns = redi[0];
    if (tid==0) pointer[b*16384 + ns*32 + step] = 1.f;
    if (n < 512) dec_in[b*DEC_STRIDE + n] = enc[((size_t)b*512+ns)*512 + n];
}

__global__ void k_final(const float* __restrict__ closs_b, float* __restrict__ out){
    if (threadIdx.x==0 && blockIdx.x==0){
        float s=0.f;
        for(int b=0;b<B;b++) s+=closs_b[b];
        out[CLOSS_OFF]=s/64.f;
    }
}

extern "C" void kernel_launch(void* const* d_in, const int* in_sizes, int n_in,
                              void* d_out, int out_size, void* d_ws, size_t ws_size,
                              hipStream_t stream){
    const float* h      = (const float*)d_in[0];
    const float* hg     = (const float*)d_in[1];
    const int*   lengths= (const int*)  d_in[2];
    const float* gumbel = (const float*)d_in[3];
    const float* W1     = (const float*)d_in[4];
    const float* W2     = (const float*)d_in[5];
    const float* wc     = (const float*)d_in[6];
    const float* v      = (const float*)d_in[7];
    const float* w_ih   = (const float*)d_in[8];
    const float* w_hh   = (const float*)d_in[9];
    const float* b_ih   = (const float*)d_in[10];
    const float* b_hh   = (const float*)d_in[11];
    const float* Wf     = (const float*)d_in[12];
    const float* bf     = (const float*)d_in[13];
    float* out = (float*)d_out;
    float* ws  = (float*)d_ws;
    float* enc = out + ENC_OFF;
    float* adj = out + ADJ_OFF;
    float* pointer = out + PTR_OFF;
    float* ep   = ws + EP_OFF;
    float* gp   = ws + GP_OFF;
    float* hidA = ws + HID0_OFF;
    float* hidB = ws + HID1_OFF;
    float* w2h  = ws + W2H_OFF;
    float* cov  = ws + COV_OFF;
    float* dec  = ws + DEC_OFF;
    float* clb  = ws + CL_OFF;
    const unsigned short* w1h = (const unsigned short*)(ws + W1H_OFF);
    const unsigned short* w1l = (const unsigned short*)(ws + W1L_OFF);

    hipLaunchKernelGGL(k_init,     dim3(512),  dim3(256), 0, stream, ws, out, hg, lengths, W1);
    hipLaunchKernelGGL(k_gather,   dim3(16384),dim3(256), 0, stream, h, lengths, ws+OFFS_OFF, enc);
    hipLaunchKernelGGL(k_gemm_mfma,dim3(1024), dim3(256), 0, stream, enc, w1h, w1l, ep);

    for (int i=0;i<MM;i++){
        const float* hin = (i&1)? hidB : hidA;
        float*       hout= (i&1)? hidA : hidB;
        hipLaunchKernelGGL(k_gruP,   dim3(512), dim3(256),  0, stream,
                           dec, hin, w_ih, w_hh, gp);
        hipLaunchKernelGGL(k_mid,    dim3(256), dim3(512),  0, stream,
                           gp, hin, hout, b_ih, b_hh, W2, Wf, bf, w2h, dec, adj, i);
        hipLaunchKernelGGL(k_scsoft, dim3(64),  dim3(1024), 0, stream,
                           ep, w2h, wc, v, lengths, gumbel, enc,
                           cov, dec, clb, pointer, i);
    }
    hipLaunchKernelGGL(k_final, dim3(1), dim3(64), 0, stream, clb, out);
}

// Round 13
// 1721.420 us; speedup vs baseline: 1.9403x; 1.2152x over previous
//
#include <hip/hip_runtime.h>
#include <math.h>

#define B 64
#define H 512
#define MAXN 512
#define U 512
#define MM 32
#define IN_SZ 543      // H + M - 1
#define DEC_STRIDE 544

// ---- d_out layout (floats) ----
#define PTR_OFF 0
#define PTR_SZ (B*MAXN*MM)            // 1,048,576
#define CLOSS_OFF (PTR_OFF + PTR_SZ)  // 1,048,576
#define ENC_OFF (CLOSS_OFF + 1)       // 1,048,577  (NOT 16B aligned)
#define ENC_SZ (B*MAXN*H)             // 16,777,216
#define ADJ_OFF (ENC_OFF + ENC_SZ)    // 17,825,793

// ---- ws layout (floats) ----
#define EP_OFF 0
#define EP_SZ (B*MAXN*U)              // 16,777,216
#define GP_OFF (EP_OFF + EP_SZ)
#define GP_SZ (4*3*B*H)               // 393,216
#define HID0_OFF (GP_OFF + GP_SZ)
#define HID1_OFF (HID0_OFF + B*H)
#define W2H_OFF  (HID1_OFF + B*H)
#define COV_OFF  (W2H_OFF + B*H)
#define SC_OFF   (COV_OFF + B*MAXN)
#define DEC_OFF  (SC_OFF + B*MAXN)
#define CL_OFF   (DEC_OFF + B*DEC_STRIDE)
#define OFFS_OFF (CL_OFF + 64)
#define W1H_OFF  (OFFS_OFF + 64)      // ushort[262144] (W1 hi bf16)
#define W1L_OFF  (W1H_OFF + 131072)   // ushort[262144] (W1 lo bf16)

typedef short bf16x8 __attribute__((ext_vector_type(8)));
typedef float f32x4  __attribute__((ext_vector_type(4)));

__device__ __forceinline__ float tanh_fast(float x){
    float e = __builtin_amdgcn_exp2f(x * 2.885390081777927f);
    return 1.0f - 2.0f * __builtin_amdgcn_rcpf(e + 1.0f);
}

__device__ __forceinline__ unsigned short f2bf(float x){
    unsigned int u = __float_as_uint(x);
    u = (u + 0x7fffu + ((u >> 16) & 1u)) >> 16;
    return (unsigned short)u;
}

// ---------------- init ----------------
__global__ void k_init(float* __restrict__ ws, float* __restrict__ out,
                       const float* __restrict__ hg, const int* __restrict__ lengths,
                       const float* __restrict__ W1){
    int gid = blockIdx.x*256 + threadIdx.x;
    int nth = gridDim.x*256;
    float* ptr = out + PTR_OFF;
    for (int i=gid;i<PTR_SZ;i+=nth) ptr[i]=0.f;
    float* dec = ws + DEC_OFF;
    for (int i=gid;i<B*DEC_STRIDE;i+=nth) dec[i]=0.f;
    float* cov = ws + COV_OFF;
    float* hid0 = ws + HID0_OFF;
    for (int i=gid;i<B*H;i+=nth){ cov[i]=0.f; hid0[i]=hg[i]; }
    unsigned short* w1h = (unsigned short*)(ws + W1H_OFF);
    unsigned short* w1l = (unsigned short*)(ws + W1L_OFF);
    for (int i=gid;i<512*512;i+=nth){
        float x = W1[i];
        unsigned short hb = f2bf(x);
        float hf = __uint_as_float(((unsigned int)hb)<<16);
        w1h[i] = hb;
        w1l[i] = f2bf(x - hf);
    }
    if (gid<64) (ws+CL_OFF)[gid]=0.f;
    if (gid==0){
        int* offs=(int*)(ws+OFFS_OFF); int acc=0;
        for(int b=0;b<B;b++){ offs[b]=acc; acc+=lengths[b]; }
    }
}

// ---------------- gather enc (2048 blocks, 8-row stride loop) ----------------
__global__ __launch_bounds__(256) void k_gather(const float* __restrict__ h,
        const int* __restrict__ lengths, const float* __restrict__ offs_f,
        float* __restrict__ enc){
    const int* offs = (const int*)offs_f;
    int t = threadIdx.x;
    int c = (t&127)*4;
    for (int row = blockIdx.x*2 + (t>>7); row < B*MAXN; row += 4096){
        int b = row >> 9, n = row & 511;
        int len = lengths[b];
        float4 v = make_float4(0.f,0.f,0.f,0.f);
        if (n < len){
            const float* p = h + (size_t)(offs[b]+n)*H + c;
            v = *(const float4*)p;
        }
        float* q = enc + (size_t)row*H + c;
        q[0]=v.x; q[1]=v.y; q[2]=v.z; q[3]=v.w;
    }
}

// ---------------- ep = enc @ W1^T via split-bf16 MFMA ----------------
// v3: A read directly from h (aligned float4, enc==h for n<len), invalid-row
// blocks skipped (ep rows never read), LDS pad 40->44 (conflict-free frag reads)
__global__ __launch_bounds__(256) void k_gemm_mfma(const float* __restrict__ h,
        const float* __restrict__ offs_f, const int* __restrict__ lengths,
        const unsigned short* __restrict__ w1h, const unsigned short* __restrict__ w1l,
        float* __restrict__ ep){
    __shared__ unsigned short sAH[128][44];
    __shared__ unsigned short sAL[128][44];
    __shared__ unsigned short sBH[128][44];
    __shared__ unsigned short sBL[128][44];
    int tid = threadIdx.x;
    int bm = blockIdx.x >> 2, bn = blockIdx.x & 3;
    int r0 = bm*128, u0 = bn*128;
    int b = r0 >> 9, n0 = r0 & 511;
    if (n0 >= lengths[b]) return;          // block-uniform: ep rows never read
    const int* offs = (const int*)offs_f;
    int hbase = offs[b] + n0;              // aligned h row base for this tile
    int wid = tid>>6, lane = tid&63;
    int wr = wid>>1, wc = wid&1;
    int lr = lane&15, lk = (lane>>4)*8;
    f32x4 acc[4][4];
#pragma unroll
    for (int i=0;i<4;i++)
#pragma unroll
        for (int j=0;j<4;j++) acc[i][j] = (f32x4){0.f,0.f,0.f,0.f};
    int rowA = tid>>2, seg = tid&3;
    for (int k0=0;k0<512;k0+=32){
#pragma unroll
        for (int half=0; half<2; ++half){
            int row = rowA + half*64;
            // A tile: h direct, aligned float4 loads; convert to hi/lo bf16
            const float* asrc = &h[(size_t)(hbase+row)*512 + k0 + seg*8];
            float4 a0 = *(const float4*)asrc;
            float4 a1 = *(const float4*)(asrc+4);
            float xa[8] = {a0.x,a0.y,a0.z,a0.w,a1.x,a1.y,a1.z,a1.w};
            bf16x8 vh, vl;
#pragma unroll
            for (int j=0;j<8;j++){
                unsigned short hb = f2bf(xa[j]);
                float hf = __uint_as_float(((unsigned int)hb)<<16);
                vh[j] = (short)hb;
                vl[j] = (short)f2bf(xa[j] - hf);
            }
            *(bf16x8*)&sAH[row][seg*8] = vh;
            *(bf16x8*)&sAL[row][seg*8] = vl;
            // B tile: pre-split bf16, direct 16B loads
            size_t bidx = (size_t)(u0+row)*512 + k0 + seg*8;
            *(bf16x8*)&sBH[row][seg*8] = *(const bf16x8*)&w1h[bidx];
            *(bf16x8*)&sBL[row][seg*8] = *(const bf16x8*)&w1l[bidx];
        }
        __syncthreads();
        bf16x8 aH[4], aL[4], bH[4], bL[4];
#pragma unroll
        for (int f=0; f<4; f++){
            aH[f] = *(const bf16x8*)&sAH[wr*64+f*16+lr][lk];
            aL[f] = *(const bf16x8*)&sAL[wr*64+f*16+lr][lk];
            bH[f] = *(const bf16x8*)&sBH[wc*64+f*16+lr][lk];
            bL[f] = *(const bf16x8*)&sBL[wc*64+f*16+lr][lk];
        }
#pragma unroll
        for (int mf=0;mf<4;mf++){
#pragma unroll
            for (int nf=0;nf<4;nf++){
                acc[mf][nf] = __builtin_amdgcn_mfma_f32_16x16x32_bf16(aH[mf], bH[nf], acc[mf][nf], 0,0,0);
                acc[mf][nf] = __builtin_amdgcn_mfma_f32_16x16x32_bf16(aH[mf], bL[nf], acc[mf][nf], 0,0,0);
                acc[mf][nf] = __builtin_amdgcn_mfma_f32_16x16x32_bf16(aL[mf], bH[nf], acc[mf][nf], 0,0,0);
            }
        }
        __syncthreads();
    }
    // D layout (m89-verified): col = lane&15, row = (lane>>4)*4 + reg
#pragma unroll
    for (int mf=0;mf<4;mf++){
#pragma unroll
        for (int nf=0;nf<4;nf++){
#pragma unroll
            for (int r=0;r<4;r++){
                int row = r0 + wr*64 + mf*16 + (lane>>4)*4 + r;
                int col = u0 + wc*64 + nf*16 + lr;
                ep[(size_t)row*512 + col] = acc[mf][nf][r];
            }
        }
    }
}

// ---------------- GRU partial dots (proven R5) ----------------
__global__ __launch_bounds__(256) void k_gruP(const float* __restrict__ dec_in,
        const float* __restrict__ hid_in,
        const float* __restrict__ w_ih, const float* __restrict__ w_hh,
        float* __restrict__ gp){
    __shared__ float As[64][36];
    __shared__ float Ws[12][36];
    int tid=threadIdx.x, b=tid&63, q=tid>>6;
    int s = blockIdx.x >> 7;
    int h0 = (int)(blockIdx.x & 127) * 4;
    const float* xs; int xstride, kbeg, kend; const float* W; int wstride;
    if (s==0){ xs=dec_in; xstride=DEC_STRIDE; kbeg=0;   kend=288;   W=w_ih; wstride=IN_SZ; }
    else if(s==1){ xs=dec_in; xstride=DEC_STRIDE; kbeg=288; kend=IN_SZ; W=w_ih; wstride=IN_SZ; }
    else if(s==2){ xs=hid_in; xstride=512; kbeg=0;   kend=256; W=w_hh; wstride=512; }
    else         { xs=hid_in; xstride=512; kbeg=256; kend=512; W=w_hh; wstride=512; }
    float a0=0.f,a1=0.f,a2=0.f;
    for (int k0=kbeg; k0<kend; k0+=32){
        for (int it=0;it<2;it++){
            int idx=tid+it*256; int row=idx>>3, c=idx&7; int k=k0+c*4;
            float4 v=make_float4(0.f,0.f,0.f,0.f);
            const float* p=&xs[row*xstride+k];
            if (k+3 < kend) v=*(const float4*)p;
            else { if(k<kend)v.x=p[0]; if(k+1<kend)v.y=p[1]; if(k+2<kend)v.z=p[2]; }
            *(float4*)&As[row][c*4]=v;
        }
        if (tid<96){
            int rr=tid>>3, c=tid&7; int g=rr>>2, qq=rr&3;
            int j=g*512 + h0+qq; int k=k0+c*4;
            float4 v=make_float4(0.f,0.f,0.f,0.f);
            const float* p=&W[(size_t)j*wstride+k];
            if (wstride==512){
                v=*(const float4*)p;
            } else {
                if(k<kend)v.x=p[0]; if(k+1<kend)v.y=p[1];
                if(k+2<kend)v.z=p[2]; if(k+3<kend)v.w=p[3];
            }
            *(float4*)&Ws[rr][c*4]=v;
        }
        __syncthreads();
#pragma unroll
        for (int kk=0;kk<32;kk+=4){
            float4 a=*(const float4*)&As[b][kk];
            float4 w0=*(const float4*)&Ws[q][kk];
            float4 w1=*(const float4*)&Ws[4+q][kk];
            float4 w2=*(const float4*)&Ws[8+q][kk];
            a0 += a.x*w0.x + a.y*w0.y + a.z*w0.z + a.w*w0.w;
            a1 += a.x*w1.x + a.y*w1.y + a.z*w1.z + a.w*w1.w;
            a2 += a.x*w2.x + a.y*w2.y + a.z*w2.z + a.w*w2.w;
        }
        __syncthreads();
    }
    int h = h0 + q;
    gp[((s*3+0)*64+b)*512 + h] = a0;
    gp[((s*3+1)*64+b)*512 + h] = a1;
    gp[((s*3+2)*64+b)*512 + h] = a2;
}

// ---------------- mid: GRU epilogue + w2h + theta (proven R5) ----------------
__global__ __launch_bounds__(512) void k_mid(const float* __restrict__ gp,
        const float* __restrict__ hid_in, float* __restrict__ hid_out,
        const float* __restrict__ b_ih, const float* __restrict__ b_hh,
        const float* __restrict__ W2, const float* __restrict__ Wf,
        const float* __restrict__ bf,
        float* __restrict__ w2h, float* __restrict__ dec_in,
        float* __restrict__ adj, int step){
    __shared__ float sH[512];
    int b = blockIdx.x >> 2, uc = blockIdx.x & 3;
    int tid = threadIdx.x;
    {
        int h = tid;
        float gI0 = gp[((0*3+0)*64+b)*512+h] + gp[((1*3+0)*64+b)*512+h];
        float gI1 = gp[((0*3+1)*64+b)*512+h] + gp[((1*3+1)*64+b)*512+h];
        float gI2 = gp[((0*3+2)*64+b)*512+h] + gp[((1*3+2)*64+b)*512+h];
        float gH0 = gp[((2*3+0)*64+b)*512+h] + gp[((3*3+0)*64+b)*512+h];
        float gH1 = gp[((2*3+1)*64+b)*512+h] + gp[((3*3+1)*64+b)*512+h];
        float gH2 = gp[((2*3+2)*64+b)*512+h] + gp[((3*3+2)*64+b)*512+h];
        float gi0=gI0+b_ih[h],     gh0=gH0+b_hh[h];
        float gi1=gI1+b_ih[512+h], gh1=gH1+b_hh[512+h];
        float gi2=gI2+b_ih[1024+h],gh2=gH2+b_hh[1024+h];
        float r=1.f/(1.f+expf(-(gi0+gh0)));
        float z=1.f/(1.f+expf(-(gi1+gh1)));
        float nn=tanhf(gi2 + r*gh2);
        float hv=(1.f-z)*nn + z*hid_in[b*512+h];
        sH[h]=hv;
        if (uc==0) hid_out[b*512+h]=hv;
    }
    __syncthreads();
    int wv=tid>>6, lane=tid&63;
    for (int ul=wv; ul<128; ul+=8){
        int u = uc*128 + ul;
        const float* wr = &W2[(size_t)u*512];
        float acc=0.f;
#pragma unroll
        for (int t=0;t<8;t++){ int k=t*64+lane; acc += wr[k]*sH[k]; }
#pragma unroll
        for (int m=1;m<64;m<<=1) acc += __shfl_xor(acc, m, 64);
        if (lane==0) w2h[b*512+u]=acc;
    }
    if (uc==0){
        for (int ul=wv; ul<31; ul+=8){
            const float* wr = &Wf[(size_t)ul*512];
            float acc=0.f;
#pragma unroll
            for (int t=0;t<8;t++){ int k=t*64+lane; acc += wr[k]*sH[k]; }
#pragma unroll
            for (int m=1;m<64;m<<=1) acc += __shfl_xor(acc, m, 64);
            if (lane==0){
                float th = 1.f/(1.f+expf(-(acc + bf[ul])));
                th = (ul < step) ? th : 0.f;
                dec_in[b*DEC_STRIDE + 512 + ul] = th;
                adj[b*992 + ul*32 + step] = th;
            }
        }
    }
}

// ---------------- scores: 1024 blocks = (b, nc of 16), 256 threads (proven R5) ----------------
__global__ __launch_bounds__(256) void k_scores(const float* __restrict__ ep,
        const float* __restrict__ w2h, const float* __restrict__ cov,
        const float* __restrict__ wc, const float* __restrict__ v,
        const int* __restrict__ lengths, float* __restrict__ sc){
    __shared__ float sW[512], sV[512], sC[512];
    int b = blockIdx.x >> 4, nc = blockIdx.x & 15;
    int len = lengths[b];
    if (nc*32 >= len) return;
    int tid=threadIdx.x;
    for (int idx=tid; idx<384; idx+=256){
        int which = idx>>7, c = (idx&127)*4;
        float4 val;
        if (which==0) val=*(const float4*)&w2h[b*512+c];
        else if (which==1) val=*(const float4*)&v[c];
        else val=*(const float4*)&wc[c];
        float* dst = (which==0)?sW:((which==1)?sV:sC);
        *(float4*)&dst[c]=val;
    }
    __syncthreads();
    int wv=tid>>6, lane=tid&63;
    float4 vv0=*(const float4*)&sV[lane*8], vv1=*(const float4*)&sV[lane*8+4];
    float4 cc0=*(const float4*)&sC[lane*8], cc1=*(const float4*)&sC[lane*8+4];
    float4 ww0=*(const float4*)&sW[lane*8], ww1=*(const float4*)&sW[lane*8+4];
#pragma unroll
    for (int r=0;r<8;r++){
        int n = nc*32 + wv*8 + r;
        float cb = cov[b*512+n];
        const float4* rr = (const float4*)&ep[((size_t)b*512+n)*512 + lane*8];
        float4 e0=rr[0], e1=rr[1];
        float acc;
        acc  = tanh_fast(e0.x + ww0.x + cb*cc0.x)*vv0.x;
        acc += tanh_fast(e0.y + ww0.y + cb*cc0.y)*vv0.y;
        acc += tanh_fast(e0.z + ww0.z + cb*cc0.z)*vv0.z;
        acc += tanh_fast(e0.w + ww0.w + cb*cc0.w)*vv0.w;
        acc += tanh_fast(e1.x + ww1.x + cb*cc1.x)*vv1.x;
        acc += tanh_fast(e1.y + ww1.y + cb*cc1.y)*vv1.y;
        acc += tanh_fast(e1.z + ww1.z + cb*cc1.z)*vv1.z;
        acc += tanh_fast(e1.w + ww1.w + cb*cc1.w)*vv1.w;
#pragma unroll
        for (int m=1;m<64;m<<=1) acc += __shfl_xor(acc, m, 64);
        if (lane==0) sc[b*512+n]=acc;
    }
}

// ---------------- soft: 64 blocks x 512 (proven R5) ----------------
__global__ __launch_bounds__(512) void k_soft(const float* __restrict__ sc,
        const float* __restrict__ gum, const int* __restrict__ lengths,
        const float* __restrict__ enc, float* __restrict__ cov,
        float* __restrict__ dec_in, float* __restrict__ closs_b,
        float* __restrict__ pointer, int step){
    __shared__ float red[512];
    __shared__ int  redi[512];
    int b=blockIdx.x, n=threadIdx.x;
    int len=lengths[b];
    float e = (n<len)? expf(sc[b*512+n]) : 0.f;
    red[n]=e; __syncthreads();
    for(int o=256;o>=1;o>>=1){ if(n<o) red[n]+=red[n+o]; __syncthreads(); }
    float Z=red[0]; __syncthreads();
    float att=e/Z;
    float c=cov[b*512+n];
    red[n]=fminf(att,c); __syncthreads();
    for(int o=256;o>=1;o>>=1){ if(n<o) red[n]+=red[n+o]; __syncthreads(); }
    if(n==0) closs_b[b]+=red[0];
    __syncthreads();
    cov[b*512+n]=c+att;
    float lg=logf(att+1e-12f)+gum[((size_t)step*64+b)*512+n];
    red[n]=lg; redi[n]=n; __syncthreads();
    for(int o=256;o>=1;o>>=1){
        if(n<o && red[n+o]>red[n]){ red[n]=red[n+o]; redi[n]=redi[n+o]; }
        __syncthreads();
    }
    int ns=redi[0];
    if(n==0) pointer[b*16384 + ns*32 + step]=1.f;
    dec_in[b*DEC_STRIDE+n]=enc[((size_t)b*512+ns)*512+n];
}

__global__ void k_final(const float* __restrict__ closs_b, float* __restrict__ out){
    if (threadIdx.x==0 && blockIdx.x==0){
        float s=0.f;
        for(int b=0;b<B;b++) s+=closs_b[b];
        out[CLOSS_OFF]=s/64.f;
    }
}

extern "C" void kernel_launch(void* const* d_in, const int* in_sizes, int n_in,
                              void* d_out, int out_size, void* d_ws, size_t ws_size,
                              hipStream_t stream){
    const float* h      = (const float*)d_in[0];
    const float* hg     = (const float*)d_in[1];
    const int*   lengths= (const int*)  d_in[2];
    const float* gumbel = (const float*)d_in[3];
    const float* W1     = (const float*)d_in[4];
    const float* W2     = (const float*)d_in[5];
    const float* wc     = (const float*)d_in[6];
    const float* v      = (const float*)d_in[7];
    const float* w_ih   = (const float*)d_in[8];
    const float* w_hh   = (const float*)d_in[9];
    const float* b_ih   = (const float*)d_in[10];
    const float* b_hh   = (const float*)d_in[11];
    const float* Wf     = (const float*)d_in[12];
    const float* bf     = (const float*)d_in[13];
    float* out = (float*)d_out;
    float* ws  = (float*)d_ws;
    float* enc = out + ENC_OFF;
    float* adj = out + ADJ_OFF;
    float* pointer = out + PTR_OFF;
    float* ep   = ws + EP_OFF;
    float* gp   = ws + GP_OFF;
    float* hidA = ws + HID0_OFF;
    float* hidB = ws + HID1_OFF;
    float* w2h  = ws + W2H_OFF;
    float* cov  = ws + COV_OFF;
    float* sc   = ws + SC_OFF;
    float* dec  = ws + DEC_OFF;
    float* clb  = ws + CL_OFF;
    const unsigned short* w1h = (const unsigned short*)(ws + W1H_OFF);
    const unsigned short* w1l = (const unsigned short*)(ws + W1L_OFF);

    hipLaunchKernelGGL(k_init,     dim3(512),  dim3(256), 0, stream, ws, out, hg, lengths, W1);
    hipLaunchKernelGGL(k_gather,   dim3(2048), dim3(256), 0, stream, h, lengths, ws+OFFS_OFF, enc);
    hipLaunchKernelGGL(k_gemm_mfma,dim3(1024), dim3(256), 0, stream,
                       h, ws+OFFS_OFF, lengths, w1h, w1l, ep);

    for (int i=0;i<MM;i++){
        const float* hin = (i&1)? hidB : hidA;
        float*       hout= (i&1)? hidA : hidB;
        hipLaunchKernelGGL(k_gruP,   dim3(512),  dim3(256), 0, stream,
                           dec, hin, w_ih, w_hh, gp);
        hipLaunchKernelGGL(k_mid,    dim3(256),  dim3(512), 0, stream,
                           gp, hin, hout, b_ih, b_hh, W2, Wf, bf, w2h, dec, adj, i);
        hipLaunchKernelGGL(k_scores, dim3(1024), dim3(256), 0, stream,
                           ep, w2h, cov, wc, v, lengths, sc);
        hipLaunchKernelGGL(k_soft,   dim3(64),   dim3(512), 0, stream,
                           sc, gumbel, lengths, enc, cov, dec, clb, pointer, i);
    }
    hipLaunchKernelGGL(k_final, dim3(1), dim3(64), 0, stream, clb, out);
}